// Round 4
// baseline (1596.958 us; speedup 1.0000x reference)
//
#include <hip/hip_runtime.h>

// RetinaNet head via bf16 MFMA implicit-GEMM (16x16x32).
// Activations: padded NHWC bf16 [plane][(H+2)(W+2)][256], zero borders.
// Block: 64co x 256px (16x16 tile), 4 waves; wave = 64co x 64px as 4x4 tiles.
// Weights are NOT staged in LDS: the blob is fragment-ordered so A-frags are
// coalesced global_load_dwordx4 (L1-hit across the 4 waves). LDS = X only
// (24.6 KB) -> 3+ blocks/CU. B-frags reuse rows across tdy: 18 ds_read_b128
// per chunk per wave feeding 144 MFMA.

typedef __attribute__((ext_vector_type(8))) short short8;
typedef __attribute__((ext_vector_type(4))) float floatx4;

#define LVLTOT 14143  // sum of padded (H+2)(W+2) over 5 levels

__device__ __forceinline__ unsigned short f2bf(float f) {
  unsigned int u = __float_as_uint(f);
  unsigned int r = (u + 0x7fffu + ((u >> 16) & 1u)) >> 16;
  return (unsigned short)r;
}

__device__ __forceinline__ void gload_lds16(const void* g, void* l) {
  __builtin_amdgcn_global_load_lds(
      (const __attribute__((address_space(1))) unsigned int*)g,
      (__attribute__((address_space(3))) unsigned int*)l, 16, 0, 0);
}

// ---- border zero: only pad cells of the 8 activation planes need zeros ----
__global__ __launch_bounds__(256) void border_zero(
    unsigned short* __restrict__ bufA, unsigned short* __restrict__ bufB) {
  static const int Wpt[5] = {102, 52, 27, 15, 9};
  static const int LOFFt[6] = {0, 10404, 13108, 13837, 14062, 14143};
  int idx = blockIdx.x * 256 + threadIdx.x;
  if (idx >= LVLTOT * 32) return;
  int px = idx >> 5, oct = idx & 31;
  int l = 0;
  while (px >= LOFFt[l + 1]) l++;
  int local = px - LOFFt[l];
  int Wp = Wpt[l];
  int r = local / Wp, c = local - r * Wp;
  if (r != 0 && r != Wp - 1 && c != 0 && c != Wp - 1) return;
  int plane = blockIdx.y;  // 0..3 bufA, 4..7 bufB (X0 aliases bufB planes 2,3)
  unsigned short* base = (plane < 4)
                             ? (bufA + (size_t)plane * LVLTOT * 256)
                             : (bufB + (size_t)(plane - 4) * LVLTOT * 256);
  floatx4 z;
  z[0] = z[1] = z[2] = z[3] = 0.f;
  *(floatx4*)(base + (size_t)px * 256 + oct * 8) = z;
}

// ---- input prep (all 5 levels, one dispatch): NCHW fp32 -> padded NHWC bf16
__global__ __launch_bounds__(256) void xprep(
    const float* __restrict__ f0, const float* __restrict__ f1,
    const float* __restrict__ f2, const float* __restrict__ f3,
    const float* __restrict__ f4, unsigned short* __restrict__ x0) {
  static const int Ht[5] = {100, 50, 25, 13, 7};
  static const int Wpt[5] = {102, 52, 27, 15, 9};
  static const int LOFFt[5] = {0, 10404, 13108, 13837, 14062};
  __shared__ float ts[8][33];
  int bx = blockIdx.x;
  int l, h, wb;
  if (bx < 400)      { l = 0; h = bx >> 2;         wb = bx & 3; }
  else if (bx < 500) { l = 1; h = (bx - 400) >> 1; wb = (bx - 400) & 1; }
  else if (bx < 525) { l = 2; h = bx - 500; wb = 0; }
  else if (bx < 538) { l = 3; h = bx - 525; wb = 0; }
  else               { l = 4; h = bx - 538; wb = 0; }
  const float* f = l == 0 ? f0 : l == 1 ? f1 : l == 2 ? f2 : l == 3 ? f3 : f4;
  int H = Ht[l], W = H, Wp = Wpt[l], loff = LOFFt[l];
  int t = threadIdx.x;
  int w0 = wb * 32;
  int n = blockIdx.z >> 5, cbk = blockIdx.z & 31;
  int cl = t >> 5, wl = t & 31;
  float v = 0.f;
  if (w0 + wl < W)
    v = f[(((size_t)n * 256 + cbk * 8 + cl) * H + h) * W + w0 + wl];
  ts[cl][wl] = v;
  __syncthreads();
  int pi = t >> 3, cj = t & 7;
  if (w0 + pi < W)
    x0[((size_t)n * LVLTOT + loff + (size_t)(h + 1) * Wp + (w0 + pi + 1)) * 256 +
       cbk * 8 + cj] = f2bf(ts[cj][pi]);
}

// ---- weight prep: w[Cout][256][9] fp32 -> blob[cb][ch][tap][quad][co64][8] bf16
struct WPArgs {
  const float* src[10];
  unsigned short* dst[10];
  int cout[10];
  int coutp[10];
};
__global__ __launch_bounds__(256) void wprep(WPArgs A) {
  int id = blockIdx.y;
  int idx = blockIdx.x * 256 + threadIdx.x;
  int coutp = A.coutp[id];
  if (idx >= coutp * 256) return;
  int co = idx >> 8, ci = idx & 255;
  const float* w = A.src[id];
  unsigned short* dst = A.dst[id];
  int cb = co >> 6, col = co & 63, chk = ci >> 5, qd = (ci >> 3) & 3, j = ci & 7;
  bool valid = co < A.cout[id];
#pragma unroll
  for (int tap = 0; tap < 9; tap++) {
    float v = valid ? w[((size_t)co * 256 + ci) * 9 + tap] : 0.f;
    dst[((((size_t)(cb * 8 + chk) * 9 + tap) * 4 + qd) * 64 + col) * 8 + j] = f2bf(v);
  }
}

// ---- tile decode (71 tiles over 5 levels) ----
__device__ __forceinline__ void decode_tile(int tile, int& l, int& h0, int& w0,
                                            int& H, int& W, int& Wp, int& loff) {
  const int Ht[5] = {100, 50, 25, 13, 7};
  const int Wpt[5] = {102, 52, 27, 15, 9};
  const int TXt[5] = {7, 4, 2, 1, 1};
  const int LOFFt[5] = {0, 10404, 13108, 13837, 14062};
  int tloc;
  if (tile < 49) { l = 0; tloc = tile; }
  else if (tile < 65) { l = 1; tloc = tile - 49; }
  else if (tile < 69) { l = 2; tloc = tile - 65; }
  else if (tile < 70) { l = 3; tloc = tile - 69; }
  else { l = 4; tloc = 0; }
  H = Ht[l]; W = H; Wp = Wpt[l]; loff = LOFFt[l];
  int ty = tloc / TXt[l], tx = tloc - ty * TXt[l];
  h0 = ty * 16; w0 = tx * 16;
}

// ---- K-loop body (needs: lane, wv, q, n16, h0, w0, Hpad, Wp, lds_x, acc) ----
// X staged per chunk (32ci) via global_load_lds; A-frags straight from global.
#define CONV_MAIN_LOOP(INP, WBLOB, CB)                                         \
  {                                                                            \
    size_t xoff[6];                                                            \
    _Pragma("unroll") for (int g = 0; g < 6; g++) {                            \
      int px = g * 64 + lane;                                                  \
      int r = px / 18, c = px - r * 18;                                        \
      int hh = h0 + r; if (hh > Hpad - 1) hh = Hpad - 1;                       \
      int ww = w0 + c; if (ww > Wp - 1) ww = Wp - 1;                           \
      xoff[g] = ((size_t)hh * Wp + ww) * 256 + wv * 8;                         \
    }                                                                          \
    for (int ch = 0; ch < 8; ch++) {                                           \
      if (ch) __syncthreads();                                                 \
      _Pragma("unroll") for (int g = 0; g < 6; g++)                            \
        gload_lds16((INP) + xoff[g] + ch * 32, lds_x + wv * 3072 + g * 512);   \
      __syncthreads();                                                         \
      const short8* xx = (const short8*)lds_x;                                 \
      const short8* wg =                                                       \
          (const short8*)((WBLOB) + ((size_t)((CB)*8 + ch)) * 18432);          \
      _Pragma("unroll") for (int tdx = 0; tdx < 3; tdx++) {                    \
        short8 bfr[6];                                                         \
        _Pragma("unroll") for (int rw = 0; rw < 6; rw++)                       \
          bfr[rw] = xx[q * 384 + (wv * 4 + rw) * 18 + n16 + tdx];              \
        _Pragma("unroll") for (int tdy = 0; tdy < 3; tdy++) {                  \
          const int tap = tdy * 3 + tdx;                                       \
          _Pragma("unroll") for (int cc = 0; cc < 4; cc++) {                   \
            short8 afr = wg[(tap * 4 + q) * 64 + cc * 16 + n16];               \
            _Pragma("unroll") for (int rr = 0; rr < 4; rr++)                   \
              acc[cc][rr] = __builtin_amdgcn_mfma_f32_16x16x32_bf16(           \
                  afr, bfr[rr + tdy], acc[cc][rr], 0, 0, 0);                   \
          }                                                                    \
        }                                                                      \
      }                                                                        \
    }                                                                          \
  }

// ---- tower conv layer (bf16 in -> bf16 out, +bias, ReLU) ----
__global__ __launch_bounds__(256, 3) void conv_tower_mfma(
    const unsigned short* __restrict__ xin, unsigned short* __restrict__ xout,
    const unsigned short* __restrict__ wblob_cls,
    const unsigned short* __restrict__ wblob_box,
    const float* __restrict__ bias_cls, const float* __restrict__ bias_box,
    int in_n_stride, int in_tw_stride) {
  __shared__ __align__(16) unsigned short lds_x[12288];
  const int t = threadIdx.x, lane = t & 63, wv = t >> 6;
  const int q = lane >> 4, n16 = lane & 15;
  int l, h0, w0, H, W, Wp, loff;
  decode_tile(blockIdx.x, l, h0, w0, H, W, Wp, loff);
  const int Hpad = H + 2;
  const int cb = blockIdx.y;
  const int n = blockIdx.z >> 1, tw = blockIdx.z & 1;
  const unsigned short* wblob = tw ? wblob_box : wblob_cls;
  const float* bias = tw ? bias_box : bias_cls;
  const unsigned short* inp =
      xin + ((size_t)n * in_n_stride + (size_t)tw * in_tw_stride + loff) * 256;
  unsigned short* outp = xout + ((size_t)(n * 2 + tw) * LVLTOT + loff) * 256;

  floatx4 acc[4][4];
#pragma unroll
  for (int i = 0; i < 4; i++)
#pragma unroll
    for (int jj = 0; jj < 4; jj++) acc[i][jj] = (floatx4){0.f, 0.f, 0.f, 0.f};

  CONV_MAIN_LOOP(inp, wblob, cb)

  // epilogue: +bias, relu, bf16, store 4 consecutive channels (8B) per lane
#pragma unroll
  for (int cc = 0; cc < 4; cc++) {
    floatx4 bb = *(const floatx4*)(bias + cb * 64 + cc * 16 + q * 4);
#pragma unroll
    for (int rr = 0; rr < 4; rr++) {
      int h = h0 + wv * 4 + rr;
      int w_ = w0 + n16;
      if (h < H && w_ < W) {
        unsigned short pk[4];
#pragma unroll
        for (int rg = 0; rg < 4; rg++)
          pk[rg] = f2bf(fmaxf(acc[cc][rr][rg] + bb[rg], 0.f));
        size_t base =
            ((size_t)(h + 1) * Wp + (w_ + 1)) * 256 + cb * 64 + cc * 16 + q * 4;
        *(unsigned long long*)(outp + base) = *(unsigned long long*)pk;
      }
    }
  }
}

// ---- merged final conv (y<12: cls cb=y; y==12: box), permuted fp32 out ----
__global__ __launch_bounds__(256, 3) void conv_final_mfma(
    const unsigned short* __restrict__ xin, float* __restrict__ out,
    const unsigned short* __restrict__ wblob_cls,
    const unsigned short* __restrict__ wblob_box,
    const float* __restrict__ bias_cls, const float* __restrict__ bias_box) {
  __shared__ __align__(16) unsigned short lds_x[12288];
  const int t = threadIdx.x, lane = t & 63, wv = t >> 6;
  const int q = lane >> 4, n16 = lane & 15;
  int l, h0, w0, H, W, Wp, loff;
  decode_tile(blockIdx.x, l, h0, w0, H, W, Wp, loff);
  const int Hpad = H + 2;
  const int yb = blockIdx.y;
  const bool is_cls = yb < 12;
  const int cb = is_cls ? yb : 0;
  const int tw = is_cls ? 0 : 1;
  const int Cout = is_cls ? 720 : 36;
  const unsigned short* wblob = is_cls ? wblob_cls : wblob_box;
  const float* bias = is_cls ? bias_cls : bias_box;
  const int n = blockIdx.z;
  const int RB[5] = {0, 90000, 112500, 118125, 119646};
  const unsigned short* inp = xin + ((size_t)(n * 2 + tw) * LVLTOT + loff) * 256;

  floatx4 acc[4][4];
#pragma unroll
  for (int i = 0; i < 4; i++)
#pragma unroll
    for (int jj = 0; jj < 4; jj++) acc[i][jj] = (floatx4){0.f, 0.f, 0.f, 0.f};

  CONV_MAIN_LOOP(inp, wblob, cb)

#pragma unroll
  for (int cc = 0; cc < 4; cc++) {
    int co0 = cb * 64 + cc * 16 + q * 4;
    if (co0 >= Cout) continue;
    floatx4 bb = *(const floatx4*)(bias + co0);
    int a = is_cls ? (co0 / 80) : (co0 >> 2);
    int col0 = is_cls ? (co0 - a * 80) : 80;
#pragma unroll
    for (int rr = 0; rr < 4; rr++) {
      int h = h0 + wv * 4 + rr;
      int w_ = w0 + n16;
      if (h < H && w_ < W) {
        size_t ridx = (size_t)RB[l] + ((size_t)h * W + w_) * 9 + a;
        floatx4 v;
#pragma unroll
        for (int rg = 0; rg < 4; rg++) v[rg] = acc[cc][rr][rg] + bb[rg];
        *(floatx4*)(out + ((size_t)n * 120087 + ridx) * 84 + col0) = v;
      }
    }
  }
}

extern "C" void kernel_launch(void* const* d_in, const int* in_sizes, int n_in,
                              void* d_out, int out_size, void* d_ws,
                              size_t ws_size, hipStream_t stream) {
  // ws layout (bytes):
  //   bufB [0, 28964864)    (X0 aliased to bufB planes 2,3: dead after layer 1)
  //   X0   [14482432, 28964864)
  //   bufA [28964864, 57929728)
  //   tower blobs 8 x 1179648 at 57929728 (cls0..3, box0..3)
  //   cls final blob 3538944 at 67366912; box final blob 294912 at 70905856
  char* ws = (char*)d_ws;
  unsigned short* bufB = (unsigned short*)(ws);
  unsigned short* X0 = (unsigned short*)(ws + 14482432);
  unsigned short* bufA = (unsigned short*)(ws + 28964864);
  unsigned short* tb[8];
  for (int i = 0; i < 8; i++)
    tb[i] = (unsigned short*)(ws + 57929728 + (size_t)i * 1179648);
  unsigned short* fb_cls = (unsigned short*)(ws + 67366912);
  unsigned short* fb_box = (unsigned short*)(ws + 70905856);

  float* out = (float*)d_out;

  border_zero<<<dim3((LVLTOT * 32 + 255) / 256, 8), 256, 0, stream>>>(bufA, bufB);
  xprep<<<dim3(545, 1, 64), 256, 0, stream>>>(
      (const float*)d_in[0], (const float*)d_in[1], (const float*)d_in[2],
      (const float*)d_in[3], (const float*)d_in[4], X0);

  WPArgs wa;
  for (int i = 0; i < 4; i++) {
    wa.src[i] = (const float*)d_in[5 + 2 * i];       // cls_w0..3
    wa.src[4 + i] = (const float*)d_in[13 + 2 * i];  // box_w0..3
    wa.dst[i] = tb[i];
    wa.dst[4 + i] = tb[4 + i];
    wa.cout[i] = wa.cout[4 + i] = 256;
    wa.coutp[i] = wa.coutp[4 + i] = 256;
  }
  wa.src[8] = (const float*)d_in[21]; wa.dst[8] = fb_cls;
  wa.cout[8] = 720; wa.coutp[8] = 768;
  wa.src[9] = (const float*)d_in[23]; wa.dst[9] = fb_box;
  wa.cout[9] = 36; wa.coutp[9] = 64;
  wprep<<<dim3(768, 10), 256, 0, stream>>>(wa);

  const float *cls_b[4], *box_b[4];
  for (int i = 0; i < 4; i++) {
    cls_b[i] = (const float*)d_in[6 + 2 * i];
    box_b[i] = (const float*)d_in[14 + 2 * i];
  }

  dim3 gt(71, 4, 4);
  conv_tower_mfma<<<gt, 256, 0, stream>>>(X0, bufA, tb[0], tb[4], cls_b[0],
                                          box_b[0], LVLTOT, 0);
  conv_tower_mfma<<<gt, 256, 0, stream>>>(bufA, bufB, tb[1], tb[5], cls_b[1],
                                          box_b[1], 2 * LVLTOT, LVLTOT);
  conv_tower_mfma<<<gt, 256, 0, stream>>>(bufB, bufA, tb[2], tb[6], cls_b[2],
                                          box_b[2], 2 * LVLTOT, LVLTOT);
  conv_tower_mfma<<<gt, 256, 0, stream>>>(bufA, bufB, tb[3], tb[7], cls_b[3],
                                          box_b[3], 2 * LVLTOT, LVLTOT);

  conv_final_mfma<<<dim3(71, 13, 2), 256, 0, stream>>>(
      bufB, out, fb_cls, fb_box, (const float*)d_in[22], (const float*)d_in[24]);
}

// Round 5
// 642.613 us; speedup vs baseline: 2.4851x; 2.4851x over previous
//
#include <hip/hip_runtime.h>

// RetinaNet head via bf16 MFMA implicit-GEMM (16x16x32) — R1 structure.
// Activations: padded NHWC bf16 [plane][(H+2)(W+2)][256], zero borders.
// Block: 64co x 256px (16x16 tile), 4 waves; wave = 64co x 64px as 4x4 tiles.
// Per ci-chunk(32): W (36KB) + X (24.6KB) staged to LDS via global_load_lds
// dwordx4; inner loop grouped by tap-column (tdx) so B-row frags are reused
// across the 3 tap-rows: 18 B + 36 A ds_read_b128 feed 144 MFMA per wave.
// All prep (NCHW->NHWC bf16, weight blobs, border zeros) fused in ONE dispatch.

typedef __attribute__((ext_vector_type(8))) short short8;
typedef __attribute__((ext_vector_type(4))) float floatx4;

#define LVLTOT 14143  // sum of padded (H+2)(W+2) over 5 levels

__device__ __forceinline__ unsigned short f2bf(float f) {
  unsigned int u = __float_as_uint(f);
  unsigned int r = (u + 0x7fffu + ((u >> 16) & 1u)) >> 16;
  return (unsigned short)r;
}

__device__ __forceinline__ void gload_lds16(const void* g, void* l) {
  __builtin_amdgcn_global_load_lds(
      (const __attribute__((address_space(1))) unsigned int*)g,
      (__attribute__((address_space(3))) unsigned int*)l, 16, 0, 0);
}

// ================= fused prep: xprep + wprep + border zero =================
// blocks [0,1090): xprep strips; [1090,3970): wprep (one co per block);
// [3970,4770): border zeroing (exact enumeration).
struct PrepArgs {
  const float* f[5];
  const float* w[10];
  unsigned short* wdst[10];
  int wblk_off[11];
  int cout[10];
  unsigned short* x0;
  unsigned short* bufA;
  unsigned short* bufB;
};

__global__ __launch_bounds__(256) void prep(PrepArgs A) {
  static const int Ht[5] = {100, 50, 25, 13, 7};
  static const int Wpt[5] = {102, 52, 27, 15, 9};
  static const int LOFFt[5] = {0, 10404, 13108, 13837, 14062};
  __shared__ float ts[32][33];
  const int bid = blockIdx.x;
  const int t = threadIdx.x;

  if (bid < 1090) {
    // ---- xprep: one 32-px row-strip, all 256 ch, one n ----
    int sid = bid % 545, n = bid / 545;
    int l, h, wb;
    if (sid < 400)      { l = 0; h = sid >> 2; wb = sid & 3; }
    else if (sid < 500) { l = 1; h = (sid - 400) >> 1; wb = (sid - 400) & 1; }
    else if (sid < 525) { l = 2; h = sid - 500; wb = 0; }
    else if (sid < 538) { l = 3; h = sid - 525; wb = 0; }
    else                { l = 4; h = sid - 538; wb = 0; }
    const float* f = A.f[l];
    int H = Ht[l], W = H, Wp = Wpt[l], loff = LOFFt[l];
    int w0 = wb * 32;
    for (int s = 0; s < 8; s++) {
      int ch0 = s * 32;
      __syncthreads();
#pragma unroll
      for (int r4 = 0; r4 < 4; r4++) {
        int ch = ch0 + (t >> 5) + r4 * 8;
        int px = w0 + (t & 31);
        float v = 0.f;
        if (px < W) v = f[(((size_t)n * 256 + ch) * H + h) * W + px];
        ts[(t >> 5) + r4 * 8][t & 31] = v;
      }
      __syncthreads();
      int pxl = t >> 3, c4 = t & 7;
      if (w0 + pxl < W) {
        unsigned short pk[4];
#pragma unroll
        for (int k = 0; k < 4; k++) pk[k] = f2bf(ts[c4 * 4 + k][pxl]);
        *(unsigned long long*)(A.x0 +
            ((size_t)n * LVLTOT + loff + (size_t)(h + 1) * Wp + (w0 + pxl + 1)) *
                256 + ch0 + c4 * 4) = *(unsigned long long*)pk;
      }
    }
    return;
  }

  if (bid < 3970) {
    // ---- wprep: block = one padded co of one tensor; thread = ci ----
    int b2 = bid - 1090;
    int tix = 0;
    while (b2 >= A.wblk_off[tix + 1]) tix++;
    int co = b2 - A.wblk_off[tix];
    int ci = t;
    bool valid = co < A.cout[tix];
    const float* w = A.w[tix];
    unsigned short* dst = A.wdst[tix];
    int cb = co >> 6, col = co & 63, chk = ci >> 5, qd = (ci >> 3) & 3, j = ci & 7;
#pragma unroll
    for (int tap = 0; tap < 9; tap++) {
      float v = valid ? w[((size_t)co * 256 + ci) * 9 + tap] : 0.f;
      dst[((((size_t)(cb * 8 + chk) * 9 + tap) * 4 + qd) * 64 + col) * 8 + j] =
          f2bf(v);
    }
    return;
  }

  // ---- border zero: items = 800 border px x 32 octs per plane ----
  {
    static const int BCUM[6] = {0, 404, 608, 712, 768, 800};
    int b3 = bid - 3970;             // [0,800): plane = b3/100
    int plane = b3 / 100;
    int item = (b3 % 100) * 256 + t; // [0,25600)
    int pxi = item >> 5, oct = item & 31;
    if (pxi >= 800) return;
    int l = 0;
    while (pxi >= BCUM[l + 1]) l++;
    int j = pxi - BCUM[l];
    int Wp = Wpt[l];
    int r, c;
    if (j < Wp)            { r = 0; c = j; }
    else if (j < 2 * Wp)   { r = Wp - 1; c = j - Wp; }
    else { int k = j - 2 * Wp; r = 1 + (k >> 1); c = (k & 1) ? Wp - 1 : 0; }
    size_t px = (size_t)LOFFt[l] + (size_t)r * Wp + c;
    unsigned short* base = (plane < 4)
                               ? (A.bufA + (size_t)plane * LVLTOT * 256)
                               : (A.bufB + (size_t)(plane - 4) * LVLTOT * 256);
    floatx4 z;
    z[0] = z[1] = z[2] = z[3] = 0.f;
    *(floatx4*)(base + px * 256 + oct * 8) = z;
  }
}

// ---- tile decode (71 tiles over 5 levels) ----
__device__ __forceinline__ void decode_tile(int tile, int& l, int& h0, int& w0,
                                            int& H, int& W, int& Wp, int& loff) {
  const int Ht[5] = {100, 50, 25, 13, 7};
  const int Wpt[5] = {102, 52, 27, 15, 9};
  const int TXt[5] = {7, 4, 2, 1, 1};
  const int LOFFt[5] = {0, 10404, 13108, 13837, 14062};
  int tloc;
  if (tile < 49) { l = 0; tloc = tile; }
  else if (tile < 65) { l = 1; tloc = tile - 49; }
  else if (tile < 69) { l = 2; tloc = tile - 65; }
  else if (tile < 70) { l = 3; tloc = tile - 69; }
  else { l = 4; tloc = 0; }
  H = Ht[l]; W = H; Wp = Wpt[l]; loff = LOFFt[l];
  int ty = tloc / TXt[l], tx = tloc - ty * TXt[l];
  h0 = ty * 16; w0 = tx * 16;
}

// ---- K-loop body (needs: lane, wv, q, n16, h0, w0, Hpad, Wp,
//      lds_w, lds_x, acc[4][4]) ----
#define CONV_MAIN_LOOP(INP, WBLOB, CB)                                         \
  {                                                                            \
    size_t xoff[6];                                                            \
    _Pragma("unroll") for (int g = 0; g < 6; g++) {                            \
      int px = g * 64 + lane;                                                  \
      int r = px / 18, c = px - r * 18;                                        \
      int hh = h0 + r; if (hh > Hpad - 1) hh = Hpad - 1;                       \
      int ww = w0 + c; if (ww > Wp - 1) ww = Wp - 1;                           \
      xoff[g] = ((size_t)hh * Wp + ww) * 256 + wv * 8;                         \
    }                                                                          \
    for (int ch = 0; ch < 8; ch++) {                                           \
      if (ch) __syncthreads();                                                 \
      const unsigned short* wsrc = (WBLOB) + ((size_t)((CB)*8 + ch)) * 18432;  \
      _Pragma("unroll") for (int i = 0; i < 9; i++)                            \
        gload_lds16(wsrc + i * 2048 + wv * 512 + lane * 8,                     \
                    lds_w + i * 2048 + wv * 512);                              \
      _Pragma("unroll") for (int g = 0; g < 6; g++)                            \
        gload_lds16((INP) + xoff[g] + ch * 32, lds_x + wv * 3072 + g * 512);   \
      __syncthreads();                                                         \
      const short8* xw = (const short8*)lds_w;                                 \
      const short8* xx = (const short8*)lds_x;                                 \
      _Pragma("unroll") for (int tdx = 0; tdx < 3; tdx++) {                    \
        short8 bfr[6];                                                         \
        _Pragma("unroll") for (int rw = 0; rw < 6; rw++)                       \
          bfr[rw] = xx[q * 384 + (wv * 4 + rw) * 18 + n16 + tdx];              \
        _Pragma("unroll") for (int tdy = 0; tdy < 3; tdy++) {                  \
          const int tap = tdy * 3 + tdx;                                       \
          _Pragma("unroll") for (int cc = 0; cc < 4; cc++) {                   \
            short8 afr = xw[(tap * 4 + q) * 64 + cc * 16 + n16];               \
            _Pragma("unroll") for (int rr = 0; rr < 4; rr++)                   \
              acc[cc][rr] = __builtin_amdgcn_mfma_f32_16x16x32_bf16(           \
                  afr, bfr[rr + tdy], acc[cc][rr], 0, 0, 0);                   \
          }                                                                    \
        }                                                                      \
      }                                                                        \
    }                                                                          \
  }

// ---- tower conv layer (bf16 in -> bf16 out, +bias, ReLU) ----
__global__ __launch_bounds__(256, 2) void conv_tower_mfma(
    const unsigned short* __restrict__ xin, unsigned short* __restrict__ xout,
    const unsigned short* __restrict__ wblob_cls,
    const unsigned short* __restrict__ wblob_box,
    const float* __restrict__ bias_cls, const float* __restrict__ bias_box,
    int in_n_stride, int in_tw_stride) {
  __shared__ __align__(16) unsigned short lds_w[18432];
  __shared__ __align__(16) unsigned short lds_x[12288];
  const int t = threadIdx.x, lane = t & 63, wv = t >> 6;
  const int q = lane >> 4, n16 = lane & 15;
  int l, h0, w0, H, W, Wp, loff;
  decode_tile(blockIdx.x, l, h0, w0, H, W, Wp, loff);
  const int Hpad = H + 2;
  const int cb = blockIdx.y;
  const int n = blockIdx.z >> 1, tw = blockIdx.z & 1;
  const unsigned short* wblob = tw ? wblob_box : wblob_cls;
  const float* bias = tw ? bias_box : bias_cls;
  const unsigned short* inp =
      xin + ((size_t)n * in_n_stride + (size_t)tw * in_tw_stride + loff) * 256;
  unsigned short* outp = xout + ((size_t)(n * 2 + tw) * LVLTOT + loff) * 256;

  floatx4 acc[4][4];
#pragma unroll
  for (int i = 0; i < 4; i++)
#pragma unroll
    for (int jj = 0; jj < 4; jj++) acc[i][jj] = (floatx4){0.f, 0.f, 0.f, 0.f};

  CONV_MAIN_LOOP(inp, wblob, cb)

  // epilogue: +bias, relu, bf16, store 4 consecutive channels (8B) per lane
#pragma unroll
  for (int cc = 0; cc < 4; cc++) {
    floatx4 bb = *(const floatx4*)(bias + cb * 64 + cc * 16 + q * 4);
#pragma unroll
    for (int rr = 0; rr < 4; rr++) {
      int h = h0 + wv * 4 + rr;
      int w_ = w0 + n16;
      if (h < H && w_ < W) {
        unsigned short pk[4];
#pragma unroll
        for (int rg = 0; rg < 4; rg++)
          pk[rg] = f2bf(fmaxf(acc[cc][rr][rg] + bb[rg], 0.f));
        size_t base =
            ((size_t)(h + 1) * Wp + (w_ + 1)) * 256 + cb * 64 + cc * 16 + q * 4;
        *(unsigned long long*)(outp + base) = *(unsigned long long*)pk;
      }
    }
  }
}

// ---- merged final conv (y<12: cls cb=y; y==12: box), permuted fp32 out ----
__global__ __launch_bounds__(256, 2) void conv_final_mfma(
    const unsigned short* __restrict__ xin, float* __restrict__ out,
    const unsigned short* __restrict__ wblob_cls,
    const unsigned short* __restrict__ wblob_box,
    const float* __restrict__ bias_cls, const float* __restrict__ bias_box) {
  __shared__ __align__(16) unsigned short lds_w[18432];
  __shared__ __align__(16) unsigned short lds_x[12288];
  const int t = threadIdx.x, lane = t & 63, wv = t >> 6;
  const int q = lane >> 4, n16 = lane & 15;
  int l, h0, w0, H, W, Wp, loff;
  decode_tile(blockIdx.x, l, h0, w0, H, W, Wp, loff);
  const int Hpad = H + 2;
  const int yb = blockIdx.y;
  const bool is_cls = yb < 12;
  const int cb = is_cls ? yb : 0;
  const int tw = is_cls ? 0 : 1;
  const int Cout = is_cls ? 720 : 36;
  const unsigned short* wblob = is_cls ? wblob_cls : wblob_box;
  const float* bias = is_cls ? bias_cls : bias_box;
  const int n = blockIdx.z;
  const int RB[5] = {0, 90000, 112500, 118125, 119646};
  const unsigned short* inp = xin + ((size_t)(n * 2 + tw) * LVLTOT + loff) * 256;

  floatx4 acc[4][4];
#pragma unroll
  for (int i = 0; i < 4; i++)
#pragma unroll
    for (int jj = 0; jj < 4; jj++) acc[i][jj] = (floatx4){0.f, 0.f, 0.f, 0.f};

  CONV_MAIN_LOOP(inp, wblob, cb)

#pragma unroll
  for (int cc = 0; cc < 4; cc++) {
    int co0 = cb * 64 + cc * 16 + q * 4;
    if (co0 >= Cout) continue;
    floatx4 bb = *(const floatx4*)(bias + co0);
    int a = is_cls ? (co0 / 80) : (co0 >> 2);
    int col0 = is_cls ? (co0 - a * 80) : 80;
#pragma unroll
    for (int rr = 0; rr < 4; rr++) {
      int h = h0 + wv * 4 + rr;
      int w_ = w0 + n16;
      if (h < H && w_ < W) {
        size_t ridx = (size_t)RB[l] + ((size_t)h * W + w_) * 9 + a;
        floatx4 v;
#pragma unroll
        for (int rg = 0; rg < 4; rg++) v[rg] = acc[cc][rr][rg] + bb[rg];
        *(floatx4*)(out + ((size_t)n * 120087 + ridx) * 84 + col0) = v;
      }
    }
  }
}

extern "C" void kernel_launch(void* const* d_in, const int* in_sizes, int n_in,
                              void* d_out, int out_size, void* d_ws,
                              size_t ws_size, hipStream_t stream) {
  // ws layout (bytes):
  //   bufB [0, 28964864)    (X0 aliased to bufB planes 2,3: dead after layer 1)
  //   X0   [14482432, 28964864)
  //   bufA [28964864, 57929728)
  //   tower blobs 8 x 1179648 at 57929728 (cls0..3, box0..3)
  //   cls final blob 3538944 at 67366912; box final blob 294912 at 70905856
  char* ws = (char*)d_ws;
  unsigned short* bufB = (unsigned short*)(ws);
  unsigned short* X0 = (unsigned short*)(ws + 14482432);
  unsigned short* bufA = (unsigned short*)(ws + 28964864);
  unsigned short* tb[8];
  for (int i = 0; i < 8; i++)
    tb[i] = (unsigned short*)(ws + 57929728 + (size_t)i * 1179648);
  unsigned short* fb_cls = (unsigned short*)(ws + 67366912);
  unsigned short* fb_box = (unsigned short*)(ws + 70905856);

  float* out = (float*)d_out;

  PrepArgs pa;
  for (int i = 0; i < 5; i++) pa.f[i] = (const float*)d_in[i];
  for (int i = 0; i < 4; i++) {
    pa.w[i] = (const float*)d_in[5 + 2 * i];       // cls_w0..3
    pa.w[4 + i] = (const float*)d_in[13 + 2 * i];  // box_w0..3
    pa.wdst[i] = tb[i];
    pa.wdst[4 + i] = tb[4 + i];
    pa.cout[i] = pa.cout[4 + i] = 256;
  }
  pa.w[8] = (const float*)d_in[21]; pa.wdst[8] = fb_cls; pa.cout[8] = 720;
  pa.w[9] = (const float*)d_in[23]; pa.wdst[9] = fb_box; pa.cout[9] = 36;
  // padded-co block counts: towers 256 each, cls 768, box 64
  int off = 0;
  for (int i = 0; i < 8; i++) { pa.wblk_off[i] = off; off += 256; }
  pa.wblk_off[8] = off; off += 768;
  pa.wblk_off[9] = off; off += 64;
  pa.wblk_off[10] = off;  // 2880
  pa.x0 = X0;
  pa.bufA = bufA;
  pa.bufB = bufB;

  prep<<<dim3(4770), 256, 0, stream>>>(pa);

  const float *cls_b[4], *box_b[4];
  for (int i = 0; i < 4; i++) {
    cls_b[i] = (const float*)d_in[6 + 2 * i];
    box_b[i] = (const float*)d_in[14 + 2 * i];
  }

  dim3 gt(71, 4, 4);
  conv_tower_mfma<<<gt, 256, 0, stream>>>(X0, bufA, tb[0], tb[4], cls_b[0],
                                          box_b[0], LVLTOT, 0);
  conv_tower_mfma<<<gt, 256, 0, stream>>>(bufA, bufB, tb[1], tb[5], cls_b[1],
                                          box_b[1], 2 * LVLTOT, LVLTOT);
  conv_tower_mfma<<<gt, 256, 0, stream>>>(bufB, bufA, tb[2], tb[6], cls_b[2],
                                          box_b[2], 2 * LVLTOT, LVLTOT);
  conv_tower_mfma<<<gt, 256, 0, stream>>>(bufA, bufB, tb[3], tb[7], cls_b[3],
                                          box_b[3], 2 * LVLTOT, LVLTOT);

  conv_final_mfma<<<dim3(71, 13, 2), 256, 0, stream>>>(
      bufB, out, fb_cls, fb_box, (const float*)d_in[22], (const float*)d_in[24]);
}